// Round 6
// baseline (1541.976 us; speedup 1.0000x reference)
//
#include <hip/hip_runtime.h>

#define NN    4096
#define BIGF  1e8f
// Scaled domain: R' = R * K2, K2 = (1/GAMMA)*log2(e).
// softmin'(a,b,c) = m - log2(exp2(m-a)+exp2(m-b)+exp2(m-c)); loss = R'/K2.
#define SQK2f 12.0112245225638540f    // sqrt(144.269504088896340736)
#define BIGK  1.4426950408889634e10f  // 1e8 * K2
#define IK2f  0.00693147180559945309f // 1/K2 = GAMMA*ln2
#define NBLK  32       // stripes of 128 rows (64 lanes x R=2)
#define SCH   16       // steps per chunk; 2 cols/step => 32 cols/chunk
#define NCI   136      // chunks: steps 0..2175 (out at s=2173)
#define OUTS  2173     // lane63: jB = 2*2173-252+1 = 4095
#define SENTU 0xFFFFFFFFu

// ---------------- fallback: single-block diagonal kernel (verified r1) ----------------
__global__ __launch_bounds__(1024) void dilate_sdtw(const float* __restrict__ pred,
                                                    const float* __restrict__ target,
                                                    float* __restrict__ out) {
    __shared__ float t_s[NN];
    __shared__ float p_s[NN];
    __shared__ float bufA[NN];
    __shared__ float bufB[NN];
    __shared__ float bufC[NN];
    const int tid = threadIdx.x;
    for (int i = tid; i < NN; i += 1024) {
        t_s[i] = target[i]; p_s[i] = pred[i];
        bufA[i] = BIGF; bufB[i] = BIGF; bufC[i] = BIGF;
    }
    __syncthreads();
    float* r2 = bufA; float* r1 = bufB; float* rn = bufC;
    for (int k = 0; k < 2 * NN - 1; ++k) {
        int ilo = k - (NN - 1); if (ilo < 0) ilo = 0;
        int ihi = (k < NN - 1) ? k : (NN - 1);
        for (int i = ilo + tid; i <= ihi; i += 1024) {
            const int j = k - i;
            float diff = t_s[i] - p_s[j];
            float d = diff * diff;
            float a = (i >= 1 && j >= 1) ? r2[i - 1] : ((k == 0) ? 0.0f : BIGF);
            float b = (i >= 1) ? r1[i - 1] : BIGF;
            float c = (j >= 1) ? r1[i] : BIGF;
            float m = fminf(a, fminf(b, c));
            float s = __expf((m - a) * 100.0f) + __expf((m - b) * 100.0f) + __expf((m - c) * 100.0f);
            rn[i] = d + m - 0.01f * __logf(s);
        }
        __syncthreads();
        float* tmp = r2; r2 = r1; r1 = rn; rn = tmp;
    }
    if (tid == 0) out[0] = r1[NN - 1];
}

// ---------------- R=2 x C=2 lane-systolic, stagger-4, delayed-shuffle, fence-free ----------------

__device__ __forceinline__ float softmin3s(float a, float b, float c) {
    float m = fminf(a, fminf(b, c));
    float e = __builtin_amdgcn_exp2f(m - a)
            + __builtin_amdgcn_exp2f(m - b)
            + __builtin_amdgcn_exp2f(m - c);
    return m - __builtin_amdgcn_logf(e);   // logf builtin = log2
}

// relaxed agent-scope atomics: bypass L1 to the coherence point, no fences.
__device__ __forceinline__ void bput(float* p, float v) {
    __hip_atomic_store((unsigned int*)p, __float_as_uint(v),
                       __ATOMIC_RELAXED, __HIP_MEMORY_SCOPE_AGENT);
}
__device__ __forceinline__ unsigned int bgetu(const float* p) {
    return __hip_atomic_load((const unsigned int*)p,
                             __ATOMIC_RELAXED, __HIP_MEMORY_SCOPE_AGENT);
}

// blocking poll-load of one 32-word boundary chunk (uniform addr across lanes)
__device__ __forceinline__ void upoll(const float* src, float* dst) {
    bool ready;
    do {
        ready = true;
#pragma unroll
        for (int q = 0; q < 32; ++q) {
            unsigned int u = bgetu(src + q);
            dst[q] = __uint_as_float(u);
            ready &= (u != SENTU);
        }
        if (!ready) __builtin_amdgcn_s_sleep(2);
    } while (!ready);
}
__device__ __forceinline__ bool utry(const float* src, float* dst) {
    bool ready = true;
#pragma unroll
    for (int q = 0; q < 32; ++q) {
        unsigned int u = bgetu(src + q);
        dst[q] = __uint_as_float(u);
        ready &= (u != SENTU);
    }
    return ready;
}

// p for one chunk: 32 consecutive columns from even `base` (clamped), 16x float2.
__device__ __forceinline__ void pload(const float* p_s, int base, float2* dst) {
#pragma unroll
    for (int q = 0; q < 16; ++q) {
        int idx = base + 2 * q;
        idx = idx < 0 ? 0 : (idx > NN - 2 ? NN - 2 : idx);
        dst[q] = *(const float2*)(p_s + idx);
    }
}

template<bool TOP, bool BOT, bool EDGE>
__device__ __forceinline__ void chunk16(
    int cs, int s0, int lane, bool l0, float t0, float t1,
    float& v0b, float& v1a, float& v1b, float& uP, float& uA, float& uB,
    const float* upc, const float2* pc,
    float* __restrict__ bnd_my, float* __restrict__ outp)
{
#pragma unroll
    for (int u = 0; u < SCH; ++u) {
        const int s  = s0 + u;
        const int jA = cs + 2 * u - 4 * lane;
        const int jB = jA + 1;
        // shuffle for NEXT step (reads v1a/v1b from step s-1) — consumed at s+1
        float nxtA = __shfl_up(v1a, 1);
        float nxtB = __shfl_up(v1b, 1);
        // up-row values for THIS step's columns
        float curA, curB;
        if (TOP) { curA = l0 ? BIGK : uA;        curB = l0 ? BIGK : uB; }
        else     { curA = l0 ? upc[2 * u] : uA;  curB = l0 ? upc[2 * u + 1] : uB; }
        float2 pj = pc[u];
        // cell (r0, jA): a=U[jA-1], b=U[jA], c=R[r0][jA-1]
        float dA0 = t0 - pj.x;
        float val0a = fmaf(dA0, dA0, softmin3s(uP, curA, v0b));
        // cell (r0, jB): a=U[jA], b=U[jB], c=val0a
        float dB0 = t0 - pj.y;
        float val0b = fmaf(dB0, dB0, softmin3s(curA, curB, val0a));
        // cell (r1, jA): a=R[r0][jA-1], b=val0a, c=R[r1][jA-1]
        float dA1 = t1 - pj.x;
        float val1a = fmaf(dA1, dA1, softmin3s(v0b, val0a, v1b));
        // cell (r1, jB): a=val0a, b=val0b, c=val1a
        float dB1 = t1 - pj.y;
        float val1b = fmaf(dB1, dB1, softmin3s(val0a, val0b, val1a));
        if (EDGE) {
            bool vA = (unsigned)jA < (unsigned)NN;
            bool vB = (unsigned)jB < (unsigned)NN;
            val0a = vA ? val0a : BIGK;  val1a = vA ? val1a : BIGK;
            val0b = vB ? val0b : BIGK;  val1b = vB ? val1b : BIGK;
            if (!BOT) {
                if (lane == 63) {
                    if (vA) bput(bnd_my + jA, val1a);
                    if (vB) bput(bnd_my + jB, val1b);
                }
            } else {
                if (lane == 63 && s == OUTS) outp[0] = val1b * IK2f;
            }
        } else if (!BOT) {
            if (lane == 63) { bput(bnd_my + jA, val1a); bput(bnd_my + jB, val1b); }
        }
        v0b = val0b; v1a = val1a; v1b = val1b;
        uP = curB; uA = nxtA; uB = nxtB;
    }
}

template<bool TOP, bool BOT>
__device__ __forceinline__ void chunk_iter(
    int ci, int lane, bool l0, float t0, float t1,
    float& v0b, float& v1a, float& v1b, float& uP, float& uA, float& uB,
    float* upX, float* upY, float2* pX, float2* pY,
    bool& haveX, bool& haveY,
    const float* p_s, const float* __restrict__ bnd_up, float* __restrict__ bnd_my,
    float* __restrict__ outp)
{
    const int cs = 32 * ci;
    if (!TOP && cs < NN) {
        if (!haveX) upoll(bnd_up + cs, upX);                       // steady state: one pass
        if (cs + 32 < NN) haveY = utry(bnd_up + cs + 32, upY);     // prefetch next chunk
        else haveY = false;
    }
    if (ci + 1 < NCI) pload(p_s, cs + 32 - 4 * lane, pY);

    const bool edge = (ci < 8) || (ci >= 128);
    if (edge) chunk16<TOP, BOT, true >(cs, SCH * ci, lane, l0, t0, t1, v0b, v1a, v1b, uP, uA, uB, upX, pX, bnd_my, outp);
    else      chunk16<TOP, BOT, false>(cs, SCH * ci, lane, l0, t0, t1, v0b, v1a, v1b, uP, uA, uB, upX, pX, bnd_my, outp);

    haveX = false;
}

template<bool TOP, bool BOT>
__device__ void stripe(int b, int lane, const float* __restrict__ target,
                       const float* p_s, float* bnd, float* outp)
{
    const float t0 = target[128 * b + 2 * lane]     * SQK2f;
    const float t1 = target[128 * b + 2 * lane + 1] * SQK2f;
    float* bnd_my = bnd + (size_t)b * NN;
    const float* bnd_up = bnd + (size_t)(b - 1) * NN;
    const bool l0 = (lane == 0);

    float v0b = BIGK, v1a = BIGK, v1b = BIGK;
    float uA = BIGK, uB = BIGK;
    float uP = (TOP && l0) ? 0.0f : BIGK;   // virtual origin R[-1][-1]=0 at cell (0,0)
    float upA[32], upB[32];
    float2 pA[16], pB[16];
    bool haveA = false, haveB = false;

    pload(p_s, -4 * lane, pA);

    for (int cp = 0; cp < NCI / 2; ++cp) {
        chunk_iter<TOP, BOT>(2 * cp,     lane, l0, t0, t1, v0b, v1a, v1b, uP, uA, uB,
                             upA, upB, pA, pB, haveA, haveB, p_s, bnd_up, bnd_my, outp);
        chunk_iter<TOP, BOT>(2 * cp + 1, lane, l0, t0, t1, v0b, v1a, v1b, uP, uA, uB,
                             upB, upA, pB, pA, haveB, haveA, p_s, bnd_up, bnd_my, outp);
    }
}

__global__ __launch_bounds__(64, 1) void sdtw_pipe5(const float* __restrict__ pred,
                                                    const float* __restrict__ target,
                                                    float* __restrict__ out,
                                                    float* __restrict__ bnd)
{
    __shared__ float p_s[NN];
    const int lane = threadIdx.x;
    const int bid = blockIdx.x;
    const int b = (bid & 7) * 4 + (bid >> 3);   // group stripe-neighbors per XCD
    for (int i = lane; i < NN; i += 64) p_s[i] = pred[i] * SQK2f;
    __syncthreads();
    if (b == 0)                stripe<true , false>(b, lane, target, p_s, bnd, out);
    else if (b == NBLK - 1)    stripe<false, true >(b, lane, target, p_s, bnd, out);
    else                       stripe<false, false>(b, lane, target, p_s, bnd, out);
}

extern "C" void kernel_launch(void* const* d_in, const int* in_sizes, int n_in,
                              void* d_out, int out_size, void* d_ws, size_t ws_size,
                              hipStream_t stream) {
    const float* pred   = (const float*)d_in[0];
    const float* target = (const float*)d_in[1];
    float* out = (float*)d_out;

    const size_t need = (size_t)NBLK * NN * sizeof(float);
    if (ws_size >= need) {
        float* bnd = (float*)d_ws;
        hipMemsetAsync(d_ws, 0xFF, need, stream);   // NaN-sentinel fill (value-carried readiness)
        sdtw_pipe5<<<dim3(NBLK), dim3(64), 0, stream>>>(pred, target, out, bnd);
    } else {
        dilate_sdtw<<<dim3(1), dim3(1024), 0, stream>>>(pred, target, out);
    }
}